// Round 2
// baseline (108.329 us; speedup 1.0000x reference)
//
#include <hip/hip_runtime.h>
#include <hip/hip_bf16.h>
#include <math.h>

#define BB 4
#define CC 64
#define DD 8
#define NN 4096
#define KS 8
#define KPS (NN / KS)          // 512 keys per split = ONE LDS stage
#define VSTR 516               // VS row stride (elems): [ch][key] layout
#define XSTR 66                // XS row stride (elems): [key][ch] layout
#define KSTR 12                // KL row stride (elems)
#define LOG2E 1.44269504088896340736f

typedef __attribute__((ext_vector_type(4))) short short4v;      // 4 bf16
typedef __attribute__((ext_vector_type(8))) short short8s;      // 8 bf16
typedef __attribute__((ext_vector_type(4))) unsigned short ushort4v;
typedef __attribute__((ext_vector_type(8))) unsigned short ushort8;  // 16B
typedef __attribute__((ext_vector_type(16))) float f32x16;

#if defined(__HIP_DEVICE_COMPILE__)
  #if __has_builtin(__builtin_amdgcn_mfma_f32_32x32x8bf16_1k)
    #define MFMA32x8(A, B, C) __builtin_amdgcn_mfma_f32_32x32x8bf16_1k(A, B, C, 0, 0, 0)
  #elif __has_builtin(__builtin_amdgcn_mfma_f32_32x32x8_bf16)
    #define MFMA32x8(A, B, C) __builtin_amdgcn_mfma_f32_32x32x8_bf16(A, B, C, 0, 0, 0)
  #else
    #error "no 32x32x8 bf16 MFMA builtin in device pass"
  #endif
  #if __has_builtin(__builtin_amdgcn_exp2f)
    #define EXP2(x) __builtin_amdgcn_exp2f(x)
  #else
    #define EXP2(x) exp2f(x)
  #endif
#else
  static __device__ __host__ inline f32x16 MFMA32x8(short4v, short4v, f32x16 c) { return c; }
  #define EXP2(x) exp2f(x)
#endif

// PV matmul on the full-rate 32x32x16 shape (A/B frag layouts symmetric).
static __device__ inline f32x16 PVMFMA(short8s A, short8s B, f32x16 c) {
#if defined(__HIP_DEVICE_COMPILE__) && __has_builtin(__builtin_amdgcn_mfma_f32_32x32x16_bf16)
    typedef __attribute__((ext_vector_type(8))) __bf16 bf16x8;
    return __builtin_amdgcn_mfma_f32_32x32x16_bf16(
        __builtin_bit_cast(bf16x8, A), __builtin_bit_cast(bf16x8, B), c, 0, 0, 0);
#else
    union { short8s v; short4v h[2]; } a, b;
    a.v = A; b.v = B;
    return MFMA32x8(a.h[1], b.h[1], MFMA32x8(a.h[0], b.h[0], c));
#endif
}

static __device__ inline short4v pack4(float a, float b, float c, float d) {
    union { short4v s; __hip_bfloat162 h[2]; } u;
    u.h[0] = __float22bfloat162_rn(make_float2(a, b));
    u.h[1] = __float22bfloat162_rn(make_float2(c, d));
    return u.s;
}
static __device__ inline unsigned packu(float lo, float hi) {
    union { __hip_bfloat162 h; unsigned u; } t;
    t.h = __float22bfloat162_rn(make_float2(lo, hi));
    return t.u;
}

// ---------------------------------------------------------------------------
// Kernel 1 (FUSED qkv+flash): each block computes the Q/K/V it needs.
//   Phase 0: stage XS[key][ch] bf16 (stride 66: conflict-free b64 reads)
//   Phase 1: K = [Wq;Wk]-stacked GEMM vs XS  -> KL (old layout)
//            Q = stacked GEMM vs global x query cols -> qf in-register
//            V = operand-swapped GEMM (A=XS, B=Wv^T) -> vacc regs
//   Phase 2: barrier; overwrite XS region with VS[ch][key] (stride 516)
//   Phase 3: barrier; flash loop (byte-identical to previous round)
// LDS: SH 67584 B (XS/VS overlay) + KL 12288 B = 79872 <= 81920 -> 2 blk/CU.
// Grid: BB * 16 qchunks * KS = 512 blocks x 512 thr, 2/CU, 4 waves/SIMD.
// ---------------------------------------------------------------------------
__global__ __launch_bounds__(512, 4) void fused_kernel(
    const float* __restrict__ x,  const float* __restrict__ Wq, const float* __restrict__ bq,
    const float* __restrict__ Wk, const float* __restrict__ bk,
    const float* __restrict__ Wv, const float* __restrict__ bv,
    unsigned* __restrict__ accb, float* __restrict__ sbuf)
{
    __shared__ unsigned short SH[512 * XSTR];  // XS then (overlaid) VS, 67584 B
    __shared__ unsigned short KL[512 * KSTR];  // 12288 B
    int tid = threadIdx.x;
    int wave = tid >> 6, lane = tid & 63;
    int l32 = lane & 31, h2 = lane >> 5;

    int blk = blockIdx.x;            // batch in low 2 bits -> XCD locality
    int b = blk & (BB - 1);
    int rest = blk >> 2;
    int split = rest & (KS - 1);
    int qchunk = rest >> 3;
    int n0 = qchunk * 256 + wave * 32;
    int m0 = split * KPS;

    const float* xb_base = x + (size_t)b * CC * NN;

    // ---- Phase 0: stage XS[key][ch] from x[b][ch][m0+key] (transpose in reg)
    {
        int cg = tid & 15, kg = tid >> 4;   // c0 = 4*cg, k0 = 16*kg
        int c0 = cg * 4, k0 = kg * 16;
        const float* xs0 = xb_base + (size_t)c0 * NN + m0 + k0;
        #pragma unroll
        for (int j = 0; j < 4; ++j) {
            float4 l0 = *(const float4*)(xs0 + 0 * NN + 4 * j);
            float4 l1 = *(const float4*)(xs0 + 1 * NN + 4 * j);
            float4 l2 = *(const float4*)(xs0 + 2 * NN + 4 * j);
            float4 l3 = *(const float4*)(xs0 + 3 * NN + 4 * j);
            const float* p0 = (const float*)&l0;
            const float* p1 = (const float*)&l1;
            const float* p2 = (const float*)&l2;
            const float* p3 = (const float*)&l3;
            #pragma unroll
            for (int i = 0; i < 4; ++i) {
                int key = k0 + 4 * j + i;
                *(short4v*)(SH + (size_t)key * XSTR + c0) =
                    pack4(p0[i], p1[i], p2[i], p3[i]);
            }
        }
    }
    __syncthreads();                 // bar1: XS ready

    // ---- stacked [Wq;Wk] A-frags (rows 0-7 = Wq, 8-15 = Wk, 16-31 = 0)
    short4v af[8];
    #pragma unroll
    for (int s = 0; s < 8; ++s) {
        float4 w4;
        if (l32 < 8) {
            w4 = *(const float4*)(Wq + (size_t)l32 * CC + s * 8 + 4 * h2);
        } else if (l32 < 16) {
            w4 = *(const float4*)(Wk + (size_t)(l32 - 8) * CC + s * 8 + 4 * h2);
        } else {
            w4 = make_float4(0.f, 0.f, 0.f, 0.f);
        }
        af[s] = pack4(w4.x, w4.y, w4.z, w4.w);
    }

    // ---- K-GEMM: this wave covers keys [wave*64, wave*64+64)
    #pragma unroll
    for (int kt = 0; kt < 2; ++kt) {
        int kb0 = wave * 64 + kt * 32;
        f32x16 acc;
        #pragma unroll
        for (int r = 0; r < 16; ++r) acc[r] = 0.f;
        #pragma unroll
        for (int s = 0; s < 8; ++s) {
            short4v bfx = *(const short4v*)(SH + (size_t)(kb0 + l32) * XSTR + s * 8 + 4 * h2);
            acc = MFMA32x8(af[s], bfx, acc);
        }
        short4v kp = pack4(acc[4] + bk[0 + 4 * h2],
                           acc[5] + bk[1 + 4 * h2],
                           acc[6] + bk[2 + 4 * h2],
                           acc[7] + bk[3 + 4 * h2]);
        *(short4v*)(KL + (size_t)(kb0 + l32) * KSTR + 4 * h2) = kp;
    }

    // ---- Q-GEMM: own 32 query columns straight from global x
    short4v qf;
    {
        const float* xq = xb_base + n0 + l32;
        f32x16 acc;
        #pragma unroll
        for (int r = 0; r < 16; ++r) acc[r] = 0.f;
        #pragma unroll
        for (int s = 0; s < 8; ++s) {
            int c0 = s * 8 + 4 * h2;
            float x0 = xq[(size_t)(c0 + 0) * NN];
            float x1 = xq[(size_t)(c0 + 1) * NN];
            float x2 = xq[(size_t)(c0 + 2) * NN];
            float x3 = xq[(size_t)(c0 + 3) * NN];
            acc = MFMA32x8(af[s], pack4(x0, x1, x2, x3), acc);
        }
        qf = pack4((acc[0] + bq[0 + 4 * h2]) * LOG2E,
                   (acc[1] + bq[1 + 4 * h2]) * LOG2E,
                   (acc[2] + bq[2 + 4 * h2]) * LOG2E,
                   (acc[3] + bq[3 + 4 * h2]) * LOG2E);
    }

    // ---- V-GEMM (operand-swapped): A = XS keys, B = Wv^T
    //      output: reg = key, lane = out-channel -> contiguous VS[ch][key] b64
    int ct = wave >> 2;              // channel tile 0/1
    int ochan = ct * 32 + l32;
    short4v bfv[8];
    #pragma unroll
    for (int s = 0; s < 8; ++s) {
        float4 w4 = *(const float4*)(Wv + (size_t)ochan * CC + s * 8 + 4 * h2);
        bfv[s] = pack4(w4.x, w4.y, w4.z, w4.w);
    }
    float bvc = bv[ochan];
    f32x16 vacc[4];
    #pragma unroll
    for (int u = 0; u < 4; ++u) {
        int kt0 = ((wave & 3) * 4 + u) * 32;
        f32x16 acc;
        #pragma unroll
        for (int r = 0; r < 16; ++r) acc[r] = 0.f;
        #pragma unroll
        for (int s = 0; s < 8; ++s) {
            short4v afx = *(const short4v*)(SH + (size_t)(kt0 + l32) * XSTR + s * 8 + 4 * h2);
            acc = MFMA32x8(afx, bfv[s], acc);
        }
        vacc[u] = acc;
    }
    __syncthreads();                 // bar2: XS fully consumed

    // ---- Phase 2: write VS[ch][key] (stride 516) over the XS region
    unsigned short* VS = SH;
    #pragma unroll
    for (int u = 0; u < 4; ++u) {
        int kbase = ((wave & 3) * 4 + u) * 32;
        #pragma unroll
        for (int g = 0; g < 4; ++g) {
            int key = kbase + 8 * g + 4 * h2;
            *(short4v*)(VS + (size_t)ochan * VSTR + key) =
                pack4(vacc[u][4 * g + 0] + bvc, vacc[u][4 * g + 1] + bvc,
                      vacc[u][4 * g + 2] + bvc, vacc[u][4 * g + 3] + bvc);
        }
    }
    __syncthreads();                 // bar3: VS + KL ready

    // ---- Phase 3: flash loop (identical to previous round)
    f32x16 o0, o1, zz;
    #pragma unroll
    for (int r = 0; r < 16; ++r) { o0[r] = 0.f; o1[r] = 0.f; zz[r] = 0.f; }
    float s0 = 0.f, s1 = 0.f, s2 = 0.f, s3 = 0.f;

    #pragma unroll
    for (int s = 0; s < 16; ++s) {
        short4v kf = *(const short4v*)(KL + (size_t)(s * 32 + l32) * KSTR + h2 * 4);
        f32x16 st = MFMA32x8(kf, qf, zz);
        float w[16];
        #pragma unroll
        for (int r = 0; r < 16; ++r) w[r] = EXP2(st[r]);
        s0 += (w[0] + w[1]) + (w[2] + w[3]);
        s1 += (w[4] + w[5]) + (w[6] + w[7]);
        s2 += (w[8] + w[9]) + (w[10] + w[11]);
        s3 += (w[12] + w[13]) + (w[14] + w[15]);

        union { short4v s; __hip_bfloat162 h[2]; } u[4];
        #pragma unroll
        for (int g = 0; g < 4; ++g) {
            u[g].h[0] = __float22bfloat162_rn(make_float2(w[4 * g],     w[4 * g + 1]));
            u[g].h[1] = __float22bfloat162_rn(make_float2(w[4 * g + 2], w[4 * g + 3]));
        }
        #pragma unroll
        for (int j = 0; j < 2; ++j) {
            int kb0 = s * 32 + j * 16 + h2 * 4;   // key base of this K=16 slice
            union { short8s v; short4v h[2]; } A, B0, B1;
            A.h[0] = u[2 * j].s;
            A.h[1] = u[2 * j + 1].s;
            B0.h[0] = *(const short4v*)(VS + (size_t)(l32)      * VSTR + kb0);
            B0.h[1] = *(const short4v*)(VS + (size_t)(l32)      * VSTR + kb0 + 8);
            B1.h[0] = *(const short4v*)(VS + (size_t)(32 + l32) * VSTR + kb0);
            B1.h[1] = *(const short4v*)(VS + (size_t)(32 + l32) * VSTR + kb0 + 8);
            o0 = PVMFMA(A.v, B0.v, o0);
            o1 = PVMFMA(A.v, B1.v, o1);
        }
    }

    // ---- raw-layout full-line stores: uint = bf162(o0[r],o1[r])
    unsigned* au = accb + (((size_t)((b * KS + split) * 128 + qchunk * 8 + wave)) << 10);
    #pragma unroll
    for (int r = 0; r < 16; ++r)
        au[r * 64 + lane] = packu(o0[r], o1[r]);

    float ssum = (s0 + s1) + (s2 + s3);
    ssum += __shfl_xor(ssum, 32);
    if (lane < 32)
        sbuf[(size_t)(b * KS + split) * NN + n0 + l32] = ssum;
}

// ---------------------------------------------------------------------------
// Kernel 2: streaming split-reduce + normalize + residual (unchanged).
// Grid: B*256 = 1024 blocks.
// ---------------------------------------------------------------------------
__global__ __launch_bounds__(256) void norm_kernel(
    const unsigned* __restrict__ accb, const float* __restrict__ sbuf,
    const float* __restrict__ x, const float* __restrict__ gamma,
    float* __restrict__ out)
{
    __shared__ float tile[16 * 65];
    __shared__ float stl[16];
    int blk = blockIdx.x;            // B * 256
    int b = blk >> 8;
    int h = blk & 255;
    int g32 = h >> 1;                // 32-query group
    int qhalf = h & 1;               // low/high 16 queries of the group
    int n0 = g32 * 32 + qhalf * 16;
    int tid = threadIdx.x;

    if (tid < 16) {
        float st = 0.f;
        #pragma unroll
        for (int sp = 0; sp < KS; ++sp)
            st += sbuf[(size_t)(b * KS + sp) * NN + n0 + tid];
        stl[tid] = 1.0f / st;
    }

    int spoff = tid >> 7;            // 0/1: even/odd split of each pass-pair
    int u = tid & 127;
    int rl = u >> 4;                 // r_local 0..7
    int lane0 = (u & 15) * 4;

    float alo[4], ahi[4];
    #pragma unroll
    for (int e = 0; e < 4; ++e) { alo[e] = 0.f; ahi[e] = 0.f; }
    #pragma unroll
    for (int p = 0; p < 4; ++p) {
        int sp = p * 2 + spoff;
        const unsigned* base = accb + (((size_t)((b * KS + sp) * 128 + g32)) << 10)
                             + qhalf * 512;
        uint4 v = *(const uint4*)(base + u * 4);
        unsigned wv[4] = {v.x, v.y, v.z, v.w};
        #pragma unroll
        for (int e = 0; e < 4; ++e) {
            alo[e] += __uint_as_float(wv[e] << 16);
            ahi[e] += __uint_as_float(wv[e] & 0xFFFF0000u);
        }
    }

    // combine the two split-halves in LDS
    #pragma unroll
    for (int e = 0; e < 4; ++e) {
        int lane = lane0 + e;
        int h2 = lane >> 5, l32 = lane & 31;
        int ql = (rl & 3) + 8 * ((rl >> 2) & 1) + 4 * h2;
        if (tid < 128) {
            tile[ql * 65 + l32]      = alo[e];
            tile[ql * 65 + 32 + l32] = ahi[e];
        }
    }
    __syncthreads();
    #pragma unroll
    for (int e = 0; e < 4; ++e) {
        int lane = lane0 + e;
        int h2 = lane >> 5, l32 = lane & 31;
        int ql = (rl & 3) + 8 * ((rl >> 2) & 1) + 4 * h2;
        if (tid >= 128) {
            tile[ql * 65 + l32]      += alo[e];
            tile[ql * 65 + 32 + l32] += ahi[e];
        }
    }
    __syncthreads();

    float gm = gamma[0];
    #pragma unroll
    for (int p2 = 0; p2 < 4; ++p2) {
        int idx = p2 * 256 + tid;
        int c = idx >> 4, ql = idx & 15;
        size_t xi = ((size_t)b * CC + c) * NN + n0 + ql;
        out[xi] = gm * tile[ql * 65 + c] * stl[ql] + x[xi];
    }
}

// ---------------------------------------------------------------------------
extern "C" void kernel_launch(void* const* d_in, const int* in_sizes, int n_in,
                              void* d_out, int out_size, void* d_ws, size_t ws_size,
                              hipStream_t stream)
{
    const float* x     = (const float*)d_in[0];
    const float* Wq    = (const float*)d_in[1];
    const float* bq    = (const float*)d_in[2];
    const float* Wk    = (const float*)d_in[3];
    const float* bk    = (const float*)d_in[4];
    const float* Wv    = (const float*)d_in[5];
    const float* bv    = (const float*)d_in[6];
    const float* gamma = (const float*)d_in[7];
    float* out = (float*)d_out;

    float* ws = (float*)d_ws;
    size_t off = 0;
    unsigned* accb = (unsigned*)(ws + off); off += (size_t)BB * KS * NN * CC / 2;   // 16.8 MB
    float* sbuf = ws + off; off += (size_t)BB * KS * NN;

    fused_kernel<<<BB * 16 * KS, 512, 0, stream>>>(x, Wq, bq, Wk, bk, Wv, bv, accb, sbuf);
    norm_kernel<<<BB * 256, 256, 0, stream>>>(accb, sbuf, x, gamma, out);
}

// Round 3
// 96.085 us; speedup vs baseline: 1.1274x; 1.1274x over previous
//
#include <hip/hip_runtime.h>
#include <hip/hip_bf16.h>
#include <math.h>

#define BB 4
#define CC 64
#define DD 8
#define NN 4096
#define KS 8
#define KPS (NN / KS)          // 512 keys per split = ONE LDS stage
#define VSTR 516               // VS row stride (elems): [ch][key] layout
#define KSTR 12                // KL row stride (elems)
#define LOG2E 1.44269504088896340736f

typedef __attribute__((ext_vector_type(4))) short short4v;      // 4 bf16
typedef __attribute__((ext_vector_type(8))) short short8s;      // 8 bf16
typedef __attribute__((ext_vector_type(4))) unsigned short ushort4v;
typedef __attribute__((ext_vector_type(8))) unsigned short ushort8;  // 16B
typedef __attribute__((ext_vector_type(16))) float f32x16;

#if defined(__HIP_DEVICE_COMPILE__)
  #if __has_builtin(__builtin_amdgcn_mfma_f32_32x32x8bf16_1k)
    #define MFMA32x8(A, B, C) __builtin_amdgcn_mfma_f32_32x32x8bf16_1k(A, B, C, 0, 0, 0)
  #elif __has_builtin(__builtin_amdgcn_mfma_f32_32x32x8_bf16)
    #define MFMA32x8(A, B, C) __builtin_amdgcn_mfma_f32_32x32x8_bf16(A, B, C, 0, 0, 0)
  #else
    #error "no 32x32x8 bf16 MFMA builtin in device pass"
  #endif
  #if __has_builtin(__builtin_amdgcn_exp2f)
    #define EXP2(x) __builtin_amdgcn_exp2f(x)
  #else
    #define EXP2(x) exp2f(x)
  #endif
#else
  static __device__ __host__ inline f32x16 MFMA32x8(short4v, short4v, f32x16 c) { return c; }
  #define EXP2(x) exp2f(x)
#endif

// PV matmul on the full-rate 32x32x16 shape (A/B frag layouts symmetric).
static __device__ inline f32x16 PVMFMA(short8s A, short8s B, f32x16 c) {
#if defined(__HIP_DEVICE_COMPILE__) && __has_builtin(__builtin_amdgcn_mfma_f32_32x32x16_bf16)
    typedef __attribute__((ext_vector_type(8))) __bf16 bf16x8;
    return __builtin_amdgcn_mfma_f32_32x32x16_bf16(
        __builtin_bit_cast(bf16x8, A), __builtin_bit_cast(bf16x8, B), c, 0, 0, 0);
#else
    union { short8s v; short4v h[2]; } a, b;
    a.v = A; b.v = B;
    return MFMA32x8(a.h[1], b.h[1], MFMA32x8(a.h[0], b.h[0], c));
#endif
}

static __device__ inline short4v pack4(float a, float b, float c, float d) {
    union { short4v s; __hip_bfloat162 h[2]; } u;
    u.h[0] = __float22bfloat162_rn(make_float2(a, b));
    u.h[1] = __float22bfloat162_rn(make_float2(c, d));
    return u.s;
}
static __device__ inline unsigned packu(float lo, float hi) {
    union { __hip_bfloat162 h; unsigned u; } t;
    t.h = __float22bfloat162_rn(make_float2(lo, hi));
    return t.u;
}

// ---------------------------------------------------------------------------
// Kernel 1: qkv GEMM, single-x-read version.  One wave per 32 columns; the
// wave loads its x fragment ONCE (bf[8]) and runs three GEMMs against it:
// V rows 0-31, V rows 32-63, stacked [Wq;Wk].  x traffic 12.6 -> 4.2 MB.
// Grid: BB * 128 = 512 blocks x 64 threads.
// ---------------------------------------------------------------------------
__global__ __launch_bounds__(64) void qkv_kernel(
    const float* __restrict__ x,  const float* __restrict__ Wq, const float* __restrict__ bq,
    const float* __restrict__ Wk, const float* __restrict__ bk,
    const float* __restrict__ Wv, const float* __restrict__ bv,
    unsigned short* __restrict__ qb, unsigned short* __restrict__ kb,
    unsigned short* __restrict__ vT)
{
    __shared__ unsigned short LQ[32 * 8];
    __shared__ unsigned short LK[32 * 8];

    int lane = threadIdx.x & 63;
    int l32 = lane & 31, h2 = lane >> 5;

    int blk = blockIdx.x;
    int b = blk & (BB - 1);
    int ng = blk >> 2;               // 0..127
    int n0 = ng * 32;

    // ---- x fragment: loaded ONCE, reused by all three GEMMs
    const float* xb = x + (size_t)b * CC * NN + n0 + l32;
    short4v bf[8];
    #pragma unroll
    for (int s = 0; s < 8; ++s) {
        int c0 = s * 8 + 4 * h2;
        float x0 = xb[(size_t)(c0 + 0) * NN];
        float x1 = xb[(size_t)(c0 + 1) * NN];
        float x2 = xb[(size_t)(c0 + 2) * NN];
        float x3 = xb[(size_t)(c0 + 3) * NN];
        bf[s] = pack4(x0, x1, x2, x3);
    }

    // ---- V GEMMs (rows 0-31, then 32-63)
    #pragma unroll
    for (int rt = 0; rt < 2; ++rt) {
        short4v af[8];
        #pragma unroll
        for (int s = 0; s < 8; ++s) {
            float4 w4 = *(const float4*)(Wv + (size_t)(rt * 32 + l32) * CC + s * 8 + 4 * h2);
            af[s] = pack4(w4.x, w4.y, w4.z, w4.w);
        }
        f32x16 acc;
        #pragma unroll
        for (int r = 0; r < 16; ++r) acc[r] = 0.f;
        #pragma unroll
        for (int s = 0; s < 8; ++s)
            acc = MFMA32x8(af[s], bf[s], acc);
        #pragma unroll
        for (int r = 0; r < 16; ++r) {
            int row = rt * 32 + (r & 3) + 8 * (r >> 2) + 4 * h2;
            float val = acc[r] + bv[row];
            __hip_bfloat16 hv = __float2bfloat16(val);
            vT[((size_t)b * CC + row) * NN + n0 + l32] = *(unsigned short*)&hv;
        }
    }

    // ---- stacked [Wq;Wk] GEMM
    {
        short4v af[8];
        #pragma unroll
        for (int s = 0; s < 8; ++s) {
            float4 w4;
            if (l32 < 8) {
                w4 = *(const float4*)(Wq + (size_t)l32 * CC + s * 8 + 4 * h2);
            } else if (l32 < 16) {
                w4 = *(const float4*)(Wk + (size_t)(l32 - 8) * CC + s * 8 + 4 * h2);
            } else {
                w4 = make_float4(0.f, 0.f, 0.f, 0.f);
            }
            af[s] = pack4(w4.x, w4.y, w4.z, w4.w);
        }
        f32x16 acc;
        #pragma unroll
        for (int r = 0; r < 16; ++r) acc[r] = 0.f;
        #pragma unroll
        for (int s = 0; s < 8; ++s)
            acc = MFMA32x8(af[s], bf[s], acc);

        short4v qp = pack4((acc[0] + bq[0 + 4 * h2]) * LOG2E,
                           (acc[1] + bq[1 + 4 * h2]) * LOG2E,
                           (acc[2] + bq[2 + 4 * h2]) * LOG2E,
                           (acc[3] + bq[3 + 4 * h2]) * LOG2E);
        short4v kp = pack4(acc[4] + bk[0 + 4 * h2],
                           acc[5] + bk[1 + 4 * h2],
                           acc[6] + bk[2 + 4 * h2],
                           acc[7] + bk[3 + 4 * h2]);
        *(short4v*)(LQ + (size_t)l32 * 8 + 4 * h2) = qp;
        *(short4v*)(LK + (size_t)l32 * 8 + 4 * h2) = kp;
        __syncthreads();
        int rw = lane & 31;
        if (lane < 32) {
            ushort8 row = *(const ushort8*)(LQ + (size_t)rw * 8);
            *(ushort8*)(qb + ((size_t)b * NN + n0 + rw) * 8) = row;
        } else {
            ushort8 row = *(const ushort8*)(LK + (size_t)rw * 8);
            *(ushort8*)(kb + ((size_t)b * NN + n0 + rw) * 8) = row;
        }
    }
}

// ---------------------------------------------------------------------------
// Kernel 2: MFMA flash, KS=8 (R1 structure, byte-identical inner loop).
// Block-index remap for accb L2 locality: blk = split*64 + qchunk*4 + b,
// so xcd = blk%8 = (qchunk*4+b)%8 is IDENTICAL for all 8 splits of a
// (b,qchunk) -> the 8 partial-O tiles (2.1 MB/XCD) stay in that XCD's L2
// for norm_kernel.  (vT tile sharing degrades 1->2 XCDs; negligible.)
// Grid: KS * 16 * BB = 512 blocks x 512 thr, 2/CU, 4 waves/SIMD.
// ---------------------------------------------------------------------------
__global__ __launch_bounds__(512, 4) void flash_kernel(
    const unsigned short* __restrict__ qb, const unsigned short* __restrict__ kb,
    const unsigned short* __restrict__ vT, unsigned* __restrict__ accb,
    float* __restrict__ sbuf)
{
    __shared__ unsigned short VS[64 * VSTR];   // 512 keys x 64 ch, 66048 B
    __shared__ unsigned short KL[512 * KSTR];  // 12288 B
    int tid = threadIdx.x;
    int wave = tid >> 6, lane = tid & 63;
    int l32 = lane & 31, h2 = lane >> 5;

    int blk = blockIdx.x;            // split*64 + qchunk*4 + b
    int b = blk & (BB - 1);
    int qchunk = (blk >> 2) & 15;
    int split = blk >> 6;
    int n0 = qchunk * 256 + wave * 32;

    short4v qf = *(const short4v*)(qb + ((size_t)b * NN + n0 + l32) * DD + h2 * 4);

    const unsigned short* kbb = kb + (size_t)b * NN * DD;
    const unsigned short* vbb = vT + (size_t)b * CC * NN;
    int m0 = split * KPS;

    // ---- stage: thread t -> channel t>>3, key segments (t&7)*8 + 64k
    {
        int ch = tid >> 3, s8 = (tid & 7) * 8;
        const unsigned short* vg = vbb + (size_t)ch * NN + m0 + s8;
        ushort8 v[8];
        #pragma unroll
        for (int k = 0; k < 8; ++k) v[k] = *(const ushort8*)(vg + 64 * k);
        ushort8 kA = *(const ushort8*)(kbb + (size_t)(m0 + tid) * DD);

        unsigned short* vp = VS + (size_t)ch * VSTR + s8;
        #pragma unroll
        for (int k = 0; k < 8; ++k) {
            *(ushort4v*)(vp + 64 * k)     = *(ushort4v*)&v[k];
            *(ushort4v*)(vp + 64 * k + 4) = *((ushort4v*)&v[k] + 1);
        }
        unsigned short* p = KL + (size_t)tid * KSTR;
        *(ushort4v*)(p)     = *(ushort4v*)&kA;
        *(ushort4v*)(p + 4) = *((ushort4v*)&kA + 1);
    }
    __syncthreads();                           // the ONLY barrier

    f32x16 o0, o1, zz;
    #pragma unroll
    for (int r = 0; r < 16; ++r) { o0[r] = 0.f; o1[r] = 0.f; zz[r] = 0.f; }
    float s0 = 0.f, s1 = 0.f, s2 = 0.f, s3 = 0.f;

    #pragma unroll
    for (int s = 0; s < 16; ++s) {
        short4v kf = *(const short4v*)(KL + (size_t)(s * 32 + l32) * KSTR + h2 * 4);
        f32x16 st = MFMA32x8(kf, qf, zz);
        float w[16];
        #pragma unroll
        for (int r = 0; r < 16; ++r) w[r] = EXP2(st[r]);
        s0 += (w[0] + w[1]) + (w[2] + w[3]);
        s1 += (w[4] + w[5]) + (w[6] + w[7]);
        s2 += (w[8] + w[9]) + (w[10] + w[11]);
        s3 += (w[12] + w[13]) + (w[14] + w[15]);

        union { short4v s; __hip_bfloat162 h[2]; } u[4];
        #pragma unroll
        for (int g = 0; g < 4; ++g) {
            u[g].h[0] = __float22bfloat162_rn(make_float2(w[4 * g],     w[4 * g + 1]));
            u[g].h[1] = __float22bfloat162_rn(make_float2(w[4 * g + 2], w[4 * g + 3]));
        }
        #pragma unroll
        for (int j = 0; j < 2; ++j) {
            int kb0 = s * 32 + j * 16 + h2 * 4;   // key base of this K=16 slice
            union { short8s v; short4v h[2]; } A, B0, B1;
            A.h[0] = u[2 * j].s;
            A.h[1] = u[2 * j + 1].s;
            B0.h[0] = *(const short4v*)(VS + (size_t)(l32)      * VSTR + kb0);
            B0.h[1] = *(const short4v*)(VS + (size_t)(l32)      * VSTR + kb0 + 8);
            B1.h[0] = *(const short4v*)(VS + (size_t)(32 + l32) * VSTR + kb0);
            B1.h[1] = *(const short4v*)(VS + (size_t)(32 + l32) * VSTR + kb0 + 8);
            o0 = PVMFMA(A.v, B0.v, o0);
            o1 = PVMFMA(A.v, B1.v, o1);
        }
    }

    // ---- raw-layout full-line stores: uint = bf162(o0[r],o1[r])
    unsigned* au = accb + (((size_t)((b * KS + split) * 128 + qchunk * 8 + wave)) << 10);
    #pragma unroll
    for (int r = 0; r < 16; ++r)
        au[r * 64 + lane] = packu(o0[r], o1[r]);

    float ssum = (s0 + s1) + (s2 + s3);
    ssum += __shfl_xor(ssum, 32);
    if (lane < 32)
        sbuf[(size_t)(b * KS + split) * NN + n0 + l32] = ssum;
}

// ---------------------------------------------------------------------------
// Kernel 3: streaming split-reduce + normalize + residual.
// Block-index decode matches flash's swizzle: t = blk&7 selects the XCD
// that produced this (b, qchunk-parity) group's partials, so all 8 accb
// split-reads hit that XCD's L2.  Bijective over (b, g32, qhalf).
// Grid: B*256 = 1024 blocks.
// ---------------------------------------------------------------------------
__global__ __launch_bounds__(256) void norm_kernel(
    const unsigned* __restrict__ accb, const float* __restrict__ sbuf,
    const float* __restrict__ x, const float* __restrict__ gamma,
    float* __restrict__ out)
{
    __shared__ float tile[16 * 65];
    __shared__ float stl[16];
    int blk = blockIdx.x;            // see decode below
    int t = blk & 7;
    int uu = blk >> 3;               // 0..127
    int b = t & 3;
    int qpar = t >> 2;               // qchunk & 1
    int qhalf = uu & 1;
    int sub = (uu >> 1) & 7;
    int qhi = uu >> 4;               // 0..7
    int qchunk = qhi * 2 + qpar;
    int g32 = qchunk * 8 + sub;      // 32-query group
    int n0 = g32 * 32 + qhalf * 16;
    int tid = threadIdx.x;

    if (tid < 16) {
        float st = 0.f;
        #pragma unroll
        for (int sp = 0; sp < KS; ++sp)
            st += sbuf[(size_t)(b * KS + sp) * NN + n0 + tid];
        stl[tid] = 1.0f / st;
    }

    int spoff = tid >> 7;            // 0/1: even/odd split of each pass-pair
    int u = tid & 127;
    int rl = u >> 4;                 // r_local 0..7
    int lane0 = (u & 15) * 4;

    float alo[4], ahi[4];
    #pragma unroll
    for (int e = 0; e < 4; ++e) { alo[e] = 0.f; ahi[e] = 0.f; }
    #pragma unroll
    for (int p = 0; p < 4; ++p) {
        int sp = p * 2 + spoff;
        const unsigned* base = accb + (((size_t)((b * KS + sp) * 128 + g32)) << 10)
                             + qhalf * 512;
        uint4 v = *(const uint4*)(base + u * 4);
        unsigned wv[4] = {v.x, v.y, v.z, v.w};
        #pragma unroll
        for (int e = 0; e < 4; ++e) {
            alo[e] += __uint_as_float(wv[e] << 16);
            ahi[e] += __uint_as_float(wv[e] & 0xFFFF0000u);
        }
    }

    // combine the two split-halves in LDS
    #pragma unroll
    for (int e = 0; e < 4; ++e) {
        int lane = lane0 + e;
        int h2 = lane >> 5, l32 = lane & 31;
        int ql = (rl & 3) + 8 * ((rl >> 2) & 1) + 4 * h2;
        if (tid < 128) {
            tile[ql * 65 + l32]      = alo[e];
            tile[ql * 65 + 32 + l32] = ahi[e];
        }
    }
    __syncthreads();
    #pragma unroll
    for (int e = 0; e < 4; ++e) {
        int lane = lane0 + e;
        int h2 = lane >> 5, l32 = lane & 31;
        int ql = (rl & 3) + 8 * ((rl >> 2) & 1) + 4 * h2;
        if (tid >= 128) {
            tile[ql * 65 + l32]      += alo[e];
            tile[ql * 65 + 32 + l32] += ahi[e];
        }
    }
    __syncthreads();

    float gm = gamma[0];
    #pragma unroll
    for (int p2 = 0; p2 < 4; ++p2) {
        int idx = p2 * 256 + tid;
        int c = idx >> 4, ql = idx & 15;
        size_t xi = ((size_t)b * CC + c) * NN + n0 + ql;
        out[xi] = gm * tile[ql * 65 + c] * stl[ql] + x[xi];
    }
}

// ---------------------------------------------------------------------------
extern "C" void kernel_launch(void* const* d_in, const int* in_sizes, int n_in,
                              void* d_out, int out_size, void* d_ws, size_t ws_size,
                              hipStream_t stream)
{
    const float* x     = (const float*)d_in[0];
    const float* Wq    = (const float*)d_in[1];
    const float* bq    = (const float*)d_in[2];
    const float* Wk    = (const float*)d_in[3];
    const float* bk    = (const float*)d_in[4];
    const float* Wv    = (const float*)d_in[5];
    const float* bv    = (const float*)d_in[6];
    const float* gamma = (const float*)d_in[7];
    float* out = (float*)d_out;

    float* ws = (float*)d_ws;
    size_t off = 0;
    unsigned short* qb = (unsigned short*)(ws + off); off += (size_t)BB * NN * DD / 2 + 64;
    unsigned short* kb = (unsigned short*)(ws + off); off += (size_t)BB * NN * DD / 2 + 64;
    unsigned short* vT = (unsigned short*)(ws + off); off += (size_t)BB * CC * NN / 2 + 64;
    unsigned* accb = (unsigned*)(ws + off); off += (size_t)BB * KS * NN * CC / 2;   // 16.8 MB
    float* sbuf = ws + off; off += (size_t)BB * KS * NN;

    qkv_kernel<<<BB * 128, 64, 0, stream>>>(x, Wq, bq, Wk, bk, Wv, bv, qb, kb, vT);
    flash_kernel<<<KS * 16 * BB, 512, 0, stream>>>(qb, kb, vT, accb, sbuf);
    norm_kernel<<<BB * 256, 256, 0, stream>>>(accb, sbuf, x, gamma, out);
}

// Round 4
// 93.452 us; speedup vs baseline: 1.1592x; 1.0282x over previous
//
#include <hip/hip_runtime.h>
#include <hip/hip_bf16.h>
#include <math.h>

#define BB 4
#define CC 64
#define DD 8
#define NN 4096
#define KS 4
#define KPS (NN / KS)          // 1024 keys per split = TWO LDS stages of 512
#define VSTR 516               // VS row stride (elems): [ch][key] layout
#define KSTR 12                // KL row stride (elems)
#define LOG2E 1.44269504088896340736f

typedef __attribute__((ext_vector_type(4))) short short4v;      // 4 bf16
typedef __attribute__((ext_vector_type(8))) short short8s;      // 8 bf16
typedef __attribute__((ext_vector_type(4))) unsigned short ushort4v;
typedef __attribute__((ext_vector_type(8))) unsigned short ushort8;  // 16B
typedef __attribute__((ext_vector_type(16))) float f32x16;

#if defined(__HIP_DEVICE_COMPILE__)
  #if __has_builtin(__builtin_amdgcn_mfma_f32_32x32x8bf16_1k)
    #define MFMA32x8(A, B, C) __builtin_amdgcn_mfma_f32_32x32x8bf16_1k(A, B, C, 0, 0, 0)
  #elif __has_builtin(__builtin_amdgcn_mfma_f32_32x32x8_bf16)
    #define MFMA32x8(A, B, C) __builtin_amdgcn_mfma_f32_32x32x8_bf16(A, B, C, 0, 0, 0)
  #else
    #error "no 32x32x8 bf16 MFMA builtin in device pass"
  #endif
  #if __has_builtin(__builtin_amdgcn_exp2f)
    #define EXP2(x) __builtin_amdgcn_exp2f(x)
  #else
    #define EXP2(x) exp2f(x)
  #endif
#else
  static __device__ __host__ inline f32x16 MFMA32x8(short4v, short4v, f32x16 c) { return c; }
  #define EXP2(x) exp2f(x)
#endif

// PV matmul on the full-rate 32x32x16 shape (A/B frag layouts symmetric).
static __device__ inline f32x16 PVMFMA(short8s A, short8s B, f32x16 c) {
#if defined(__HIP_DEVICE_COMPILE__) && __has_builtin(__builtin_amdgcn_mfma_f32_32x32x16_bf16)
    typedef __attribute__((ext_vector_type(8))) __bf16 bf16x8;
    return __builtin_amdgcn_mfma_f32_32x32x16_bf16(
        __builtin_bit_cast(bf16x8, A), __builtin_bit_cast(bf16x8, B), c, 0, 0, 0);
#else
    union { short8s v; short4v h[2]; } a, b;
    a.v = A; b.v = B;
    return MFMA32x8(a.h[1], b.h[1], MFMA32x8(a.h[0], b.h[0], c));
#endif
}

static __device__ inline short4v pack4(float a, float b, float c, float d) {
    union { short4v s; __hip_bfloat162 h[2]; } u;
    u.h[0] = __float22bfloat162_rn(make_float2(a, b));
    u.h[1] = __float22bfloat162_rn(make_float2(c, d));
    return u.s;
}
static __device__ inline unsigned packu(float lo, float hi) {
    union { __hip_bfloat162 h; unsigned u; } t;
    t.h = __float22bfloat162_rn(make_float2(lo, hi));
    return t.u;
}

// ---------------------------------------------------------------------------
// Kernel 1: qkv GEMM, single-x-read version (unchanged from R3).
// Grid: BB * 128 = 512 blocks x 64 threads.
// ---------------------------------------------------------------------------
__global__ __launch_bounds__(64) void qkv_kernel(
    const float* __restrict__ x,  const float* __restrict__ Wq, const float* __restrict__ bq,
    const float* __restrict__ Wk, const float* __restrict__ bk,
    const float* __restrict__ Wv, const float* __restrict__ bv,
    unsigned short* __restrict__ qb, unsigned short* __restrict__ kb,
    unsigned short* __restrict__ vT)
{
    __shared__ unsigned short LQ[32 * 8];
    __shared__ unsigned short LK[32 * 8];

    int lane = threadIdx.x & 63;
    int l32 = lane & 31, h2 = lane >> 5;

    int blk = blockIdx.x;
    int b = blk & (BB - 1);
    int ng = blk >> 2;               // 0..127
    int n0 = ng * 32;

    // ---- x fragment: loaded ONCE, reused by all three GEMMs
    const float* xb = x + (size_t)b * CC * NN + n0 + l32;
    short4v bf[8];
    #pragma unroll
    for (int s = 0; s < 8; ++s) {
        int c0 = s * 8 + 4 * h2;
        float x0 = xb[(size_t)(c0 + 0) * NN];
        float x1 = xb[(size_t)(c0 + 1) * NN];
        float x2 = xb[(size_t)(c0 + 2) * NN];
        float x3 = xb[(size_t)(c0 + 3) * NN];
        bf[s] = pack4(x0, x1, x2, x3);
    }

    // ---- V GEMMs (rows 0-31, then 32-63)
    #pragma unroll
    for (int rt = 0; rt < 2; ++rt) {
        short4v af[8];
        #pragma unroll
        for (int s = 0; s < 8; ++s) {
            float4 w4 = *(const float4*)(Wv + (size_t)(rt * 32 + l32) * CC + s * 8 + 4 * h2);
            af[s] = pack4(w4.x, w4.y, w4.z, w4.w);
        }
        f32x16 acc;
        #pragma unroll
        for (int r = 0; r < 16; ++r) acc[r] = 0.f;
        #pragma unroll
        for (int s = 0; s < 8; ++s)
            acc = MFMA32x8(af[s], bf[s], acc);
        #pragma unroll
        for (int r = 0; r < 16; ++r) {
            int row = rt * 32 + (r & 3) + 8 * (r >> 2) + 4 * h2;
            float val = acc[r] + bv[row];
            __hip_bfloat16 hv = __float2bfloat16(val);
            vT[((size_t)b * CC + row) * NN + n0 + l32] = *(unsigned short*)&hv;
        }
    }

    // ---- stacked [Wq;Wk] GEMM
    {
        short4v af[8];
        #pragma unroll
        for (int s = 0; s < 8; ++s) {
            float4 w4;
            if (l32 < 8) {
                w4 = *(const float4*)(Wq + (size_t)l32 * CC + s * 8 + 4 * h2);
            } else if (l32 < 16) {
                w4 = *(const float4*)(Wk + (size_t)(l32 - 8) * CC + s * 8 + 4 * h2);
            } else {
                w4 = make_float4(0.f, 0.f, 0.f, 0.f);
            }
            af[s] = pack4(w4.x, w4.y, w4.z, w4.w);
        }
        f32x16 acc;
        #pragma unroll
        for (int r = 0; r < 16; ++r) acc[r] = 0.f;
        #pragma unroll
        for (int s = 0; s < 8; ++s)
            acc = MFMA32x8(af[s], bf[s], acc);

        short4v qp = pack4((acc[0] + bq[0 + 4 * h2]) * LOG2E,
                           (acc[1] + bq[1 + 4 * h2]) * LOG2E,
                           (acc[2] + bq[2 + 4 * h2]) * LOG2E,
                           (acc[3] + bq[3 + 4 * h2]) * LOG2E);
        short4v kp = pack4(acc[4] + bk[0 + 4 * h2],
                           acc[5] + bk[1 + 4 * h2],
                           acc[6] + bk[2 + 4 * h2],
                           acc[7] + bk[3 + 4 * h2]);
        *(short4v*)(LQ + (size_t)l32 * 8 + 4 * h2) = qp;
        *(short4v*)(LK + (size_t)l32 * 8 + 4 * h2) = kp;
        __syncthreads();
        int rw = lane & 31;
        if (lane < 32) {
            ushort8 row = *(const ushort8*)(LQ + (size_t)rw * 8);
            *(ushort8*)(qb + ((size_t)b * NN + n0 + rw) * 8) = row;
        } else {
            ushort8 row = *(const ushort8*)(LK + (size_t)rw * 8);
            *(ushort8*)(kb + ((size_t)b * NN + n0 + rw) * 8) = row;
        }
    }
}

// ---------------------------------------------------------------------------
// Kernel 2: MFMA flash, KS=4: 1024 keys/split as TWO double-buffered stages.
// LDS = 2 x (66048 + 12288) = 156672 B -> 1 block/CU (grid 256 = 1/CU).
// Stage-1 global loads issue BEFORE stage-0 compute (T14 async-split) so
// HBM latency hides under the 16-iter MFMA+exp loop.
// Denominator via PVMFMA with B=ones (sum moves VALU -> MFMA pipe, and
// matches the numerator's bf16-rounded weights exactly).
// Swizzle: blk = split*64 + qchunk*4 + b (accb XCD locality for norm).
// ---------------------------------------------------------------------------
__global__ __launch_bounds__(512, 2) void flash_kernel(
    const unsigned short* __restrict__ qb, const unsigned short* __restrict__ kb,
    const unsigned short* __restrict__ vT, unsigned* __restrict__ accb,
    float* __restrict__ sbuf)
{
    __shared__ unsigned short VS[2][64 * VSTR];   // 2 x 66048 B
    __shared__ unsigned short KL[2][512 * KSTR];  // 2 x 12288 B
    int tid = threadIdx.x;
    int wave = tid >> 6, lane = tid & 63;
    int l32 = lane & 31, h2 = lane >> 5;

    int blk = blockIdx.x;            // split*64 + qchunk*4 + b
    int b = blk & (BB - 1);
    int qchunk = (blk >> 2) & 15;
    int split = blk >> 6;            // 0..3
    int n0 = qchunk * 256 + wave * 32;

    short4v qf = *(const short4v*)(qb + ((size_t)b * NN + n0 + l32) * DD + h2 * 4);

    const unsigned short* kbb = kb + (size_t)b * NN * DD;
    const unsigned short* vbb = vT + (size_t)b * CC * NN;
    int m0 = split * KPS;

    int ch = tid >> 3, s8 = (tid & 7) * 8;
    const unsigned short* vg = vbb + (size_t)ch * NN + m0 + s8;

    // ---- stage 0: load + LDS write
    {
        ushort8 v[8];
        #pragma unroll
        for (int k = 0; k < 8; ++k) v[k] = *(const ushort8*)(vg + 64 * k);
        ushort8 kA = *(const ushort8*)(kbb + (size_t)(m0 + tid) * DD);

        unsigned short* vp = VS[0] + (size_t)ch * VSTR + s8;
        #pragma unroll
        for (int k = 0; k < 8; ++k) {
            *(ushort4v*)(vp + 64 * k)     = *(ushort4v*)&v[k];
            *(ushort4v*)(vp + 64 * k + 4) = *((ushort4v*)&v[k] + 1);
        }
        unsigned short* p = KL[0] + (size_t)tid * KSTR;
        *(ushort4v*)(p)     = *(ushort4v*)&kA;
        *(ushort4v*)(p + 4) = *((ushort4v*)&kA + 1);
    }
    __syncthreads();                 // stage 0 ready

    // ---- issue stage-1 loads NOW; LDS write deferred past stage-0 compute
    ushort8 v1[8];
    #pragma unroll
    for (int k = 0; k < 8; ++k) v1[k] = *(const ushort8*)(vg + 512 + 64 * k);
    ushort8 kA1 = *(const ushort8*)(kbb + (size_t)(m0 + 512 + tid) * DD);

    // ones B-fragment (bf16 1.0 in every slot) for the denominator MFMA
    union { short8s v; unsigned short e[8]; } ones;
    #pragma unroll
    for (int i = 0; i < 8; ++i) ones.e[i] = 0x3F80;

    f32x16 o0, o1, oS, zz;
    #pragma unroll
    for (int r = 0; r < 16; ++r) { o0[r] = 0.f; o1[r] = 0.f; oS[r] = 0.f; zz[r] = 0.f; }

#define COMPUTE(ST)                                                              \
    {                                                                            \
        _Pragma("unroll")                                                        \
        for (int s = 0; s < 16; ++s) {                                           \
            short4v kf = *(const short4v*)(KL[ST] + (size_t)(s * 32 + l32) * KSTR + h2 * 4); \
            f32x16 sv = MFMA32x8(kf, qf, zz);                                    \
            float w[16];                                                         \
            _Pragma("unroll")                                                    \
            for (int r = 0; r < 16; ++r) w[r] = EXP2(sv[r]);                     \
            union { short4v s; __hip_bfloat162 h[2]; } u[4];                     \
            _Pragma("unroll")                                                    \
            for (int g = 0; g < 4; ++g) {                                        \
                u[g].h[0] = __float22bfloat162_rn(make_float2(w[4 * g],     w[4 * g + 1])); \
                u[g].h[1] = __float22bfloat162_rn(make_float2(w[4 * g + 2], w[4 * g + 3])); \
            }                                                                    \
            _Pragma("unroll")                                                    \
            for (int j = 0; j < 2; ++j) {                                        \
                int kb0 = s * 32 + j * 16 + h2 * 4;                              \
                union { short8s v; short4v h[2]; } A, B0, B1;                    \
                A.h[0] = u[2 * j].s;                                             \
                A.h[1] = u[2 * j + 1].s;                                         \
                B0.h[0] = *(const short4v*)(VS[ST] + (size_t)(l32)      * VSTR + kb0);     \
                B0.h[1] = *(const short4v*)(VS[ST] + (size_t)(l32)      * VSTR + kb0 + 8); \
                B1.h[0] = *(const short4v*)(VS[ST] + (size_t)(32 + l32) * VSTR + kb0);     \
                B1.h[1] = *(const short4v*)(VS[ST] + (size_t)(32 + l32) * VSTR + kb0 + 8); \
                o0 = PVMFMA(A.v, B0.v, o0);                                      \
                o1 = PVMFMA(A.v, B1.v, o1);                                      \
                oS = PVMFMA(A.v, ones.v, oS);                                    \
            }                                                                    \
        }                                                                        \
    }

    COMPUTE(0)

    // ---- stage 1: LDS write (loads long since landed), barrier, compute
    {
        unsigned short* vp = VS[1] + (size_t)ch * VSTR + s8;
        #pragma unroll
        for (int k = 0; k < 8; ++k) {
            *(ushort4v*)(vp + 64 * k)     = *(ushort4v*)&v1[k];
            *(ushort4v*)(vp + 64 * k + 4) = *((ushort4v*)&v1[k] + 1);
        }
        unsigned short* p = KL[1] + (size_t)tid * KSTR;
        *(ushort4v*)(p)     = *(ushort4v*)&kA1;
        *(ushort4v*)(p + 4) = *((ushort4v*)&kA1 + 1);
    }
    __syncthreads();                 // stage 1 ready

    COMPUTE(1)
#undef COMPUTE

    // ---- raw-layout full-line stores: uint = bf162(o0[r],o1[r])
    unsigned* au = accb + (((size_t)((b * KS + split) * 128 + qchunk * 8 + wave)) << 10);
    #pragma unroll
    for (int r = 0; r < 16; ++r)
        au[r * 64 + lane] = packu(o0[r], o1[r]);

    // ---- denominator: oS[r] = denom for q_local=(r&3)+8*(r>>2)+4*h2 (all l32)
    float* sb = sbuf + (size_t)(b * KS + split) * NN + n0;
    #pragma unroll
    for (int r = 0; r < 16; ++r) {
        int ql = (r & 3) + 8 * (r >> 2) + 4 * h2;
        if (l32 == r) sb[ql] = oS[r];
    }
}

// ---------------------------------------------------------------------------
// Kernel 3: streaming split-reduce + normalize + residual (KS=4: 2 passes).
// Decode matches flash's swizzle for accb XCD locality.
// Grid: B*256 = 1024 blocks.
// ---------------------------------------------------------------------------
__global__ __launch_bounds__(256) void norm_kernel(
    const unsigned* __restrict__ accb, const float* __restrict__ sbuf,
    const float* __restrict__ x, const float* __restrict__ gamma,
    float* __restrict__ out)
{
    __shared__ float tile[16 * 65];
    __shared__ float stl[16];
    int blk = blockIdx.x;            // see decode below
    int t = blk & 7;
    int uu = blk >> 3;               // 0..127
    int b = t & 3;
    int qpar = t >> 2;               // qchunk & 1
    int qhalf = uu & 1;
    int sub = (uu >> 1) & 7;
    int qhi = uu >> 4;               // 0..7
    int qchunk = qhi * 2 + qpar;
    int g32 = qchunk * 8 + sub;      // 32-query group
    int n0 = g32 * 32 + qhalf * 16;
    int tid = threadIdx.x;

    if (tid < 16) {
        float st = 0.f;
        #pragma unroll
        for (int sp = 0; sp < KS; ++sp)
            st += sbuf[(size_t)(b * KS + sp) * NN + n0 + tid];
        stl[tid] = 1.0f / st;
    }

    int spoff = tid >> 7;            // 0/1: even/odd split of each pass-pair
    int u = tid & 127;
    int rl = u >> 4;                 // r_local 0..7
    int lane0 = (u & 15) * 4;

    float alo[4], ahi[4];
    #pragma unroll
    for (int e = 0; e < 4; ++e) { alo[e] = 0.f; ahi[e] = 0.f; }
    #pragma unroll
    for (int p = 0; p < KS / 2; ++p) {
        int sp = p * 2 + spoff;
        const unsigned* base = accb + (((size_t)((b * KS + sp) * 128 + g32)) << 10)
                             + qhalf * 512;
        uint4 v = *(const uint4*)(base + u * 4);
        unsigned wv[4] = {v.x, v.y, v.z, v.w};
        #pragma unroll
        for (int e = 0; e < 4; ++e) {
            alo[e] += __uint_as_float(wv[e] << 16);
            ahi[e] += __uint_as_float(wv[e] & 0xFFFF0000u);
        }
    }

    // combine the two split-halves in LDS
    #pragma unroll
    for (int e = 0; e < 4; ++e) {
        int lane = lane0 + e;
        int h2 = lane >> 5, l32 = lane & 31;
        int ql = (rl & 3) + 8 * ((rl >> 2) & 1) + 4 * h2;
        if (tid < 128) {
            tile[ql * 65 + l32]      = alo[e];
            tile[ql * 65 + 32 + l32] = ahi[e];
        }
    }
    __syncthreads();
    #pragma unroll
    for (int e = 0; e < 4; ++e) {
        int lane = lane0 + e;
        int h2 = lane >> 5, l32 = lane & 31;
        int ql = (rl & 3) + 8 * ((rl >> 2) & 1) + 4 * h2;
        if (tid >= 128) {
            tile[ql * 65 + l32]      += alo[e];
            tile[ql * 65 + 32 + l32] += ahi[e];
        }
    }
    __syncthreads();

    float gm = gamma[0];
    #pragma unroll
    for (int p2 = 0; p2 < 4; ++p2) {
        int idx = p2 * 256 + tid;
        int c = idx >> 4, ql = idx & 15;
        size_t xi = ((size_t)b * CC + c) * NN + n0 + ql;
        out[xi] = gm * tile[ql * 65 + c] * stl[ql] + x[xi];
    }
}

// ---------------------------------------------------------------------------
extern "C" void kernel_launch(void* const* d_in, const int* in_sizes, int n_in,
                              void* d_out, int out_size, void* d_ws, size_t ws_size,
                              hipStream_t stream)
{
    const float* x     = (const float*)d_in[0];
    const float* Wq    = (const float*)d_in[1];
    const float* bq    = (const float*)d_in[2];
    const float* Wk    = (const float*)d_in[3];
    const float* bk    = (const float*)d_in[4];
    const float* Wv    = (const float*)d_in[5];
    const float* bv    = (const float*)d_in[6];
    const float* gamma = (const float*)d_in[7];
    float* out = (float*)d_out;

    float* ws = (float*)d_ws;
    size_t off = 0;
    unsigned short* qb = (unsigned short*)(ws + off); off += (size_t)BB * NN * DD / 2 + 64;
    unsigned short* kb = (unsigned short*)(ws + off); off += (size_t)BB * NN * DD / 2 + 64;
    unsigned short* vT = (unsigned short*)(ws + off); off += (size_t)BB * CC * NN / 2 + 64;
    unsigned* accb = (unsigned*)(ws + off); off += (size_t)BB * KS * NN * CC / 2;   // 8.4 MB
    float* sbuf = ws + off; off += (size_t)BB * KS * NN;

    qkv_kernel<<<BB * 128, 64, 0, stream>>>(x, Wq, bq, Wk, bk, Wv, bv, qb, kb, vT);
    flash_kernel<<<KS * 16 * BB, 512, 0, stream>>>(qb, kb, vT, accb, sbuf);
    norm_kernel<<<BB * 256, 256, 0, stream>>>(accb, sbuf, x, gamma, out);
}